// Round 1
// baseline (774.333 us; speedup 1.0000x reference)
//
#include <hip/hip_runtime.h>
#include <math.h>

#define N_NODES 20000
#define E_EDGES 200000
#define K1_KEEP 10000
#define K2_KEEP 5000
#define HIDC 128
#define NHEAD 4
#define FDIM 512   // NHEAD*HIDC
#define NEG 0.2f

__device__ __forceinline__ float leaky(float x){ return x > 0.f ? x : NEG * x; }
__device__ __forceinline__ float elu(float x){ return x > 0.f ? x : expm1f(x); }
// monotone float->uint key (ascending)
__device__ __forceinline__ unsigned ordkey(float f){
    unsigned u = __float_as_uint(f);
    return (u & 0x80000000u) ? ~u : (u | 0x80000000u);
}

// ---------------- GEMM: out[n x 512] = A[n x K] @ W[K x 512] ----------------
// 32 rows/block, 256 threads, each thread owns cols {t, t+256} for 32 rows.
template<int K>
__global__ __launch_bounds__(256) void gemm_rm(const float* __restrict__ A,
                                               const float* __restrict__ W,
                                               float* __restrict__ out, int n)
{
    __shared__ float tile[32 * 64];
    int t = threadIdx.x;
    int row0 = blockIdx.x * 32;
    float acc0[32], acc1[32];
#pragma unroll
    for (int r = 0; r < 32; ++r){ acc0[r] = 0.f; acc1[r] = 0.f; }

    for (int kc = 0; kc < K; kc += 64){
        // stage 32x64 A tile
#pragma unroll
        for (int i = 0; i < 8; ++i){
            int e = t + i * 256;
            int r = e >> 6, c = e & 63;
            int gr = row0 + r;
            tile[e] = (gr < n) ? A[(size_t)gr * K + kc + c] : 0.f;
        }
        __syncthreads();
        for (int kk = 0; kk < 64; kk += 4){
            float w0[4], w1[4];
#pragma unroll
            for (int u = 0; u < 4; ++u){
                w0[u] = W[(size_t)(kc + kk + u) * 512 + t];
                w1[u] = W[(size_t)(kc + kk + u) * 512 + t + 256];
            }
#pragma unroll
            for (int r = 0; r < 32; ++r){
                const float4 av = *reinterpret_cast<const float4*>(&tile[r * 64 + kk]);
                acc0[r] += av.x * w0[0] + av.y * w0[1] + av.z * w0[2] + av.w * w0[3];
                acc1[r] += av.x * w1[0] + av.y * w1[1] + av.z * w1[2] + av.w * w1[3];
            }
        }
        __syncthreads();
    }
#pragma unroll
    for (int r = 0; r < 32; ++r){
        int gr = row0 + r;
        if (gr < n){
            out[(size_t)gr * 512 + t]       = acc0[r];
            out[(size_t)gr * 512 + t + 256] = acc1[r];
        }
    }
}

// ------------- attention scores: asrc[n][h], adst[n][h] ---------------------
__global__ __launch_bounds__(256) void attn_scores(const float* __restrict__ h,
        const float* __restrict__ a_src, const float* __restrict__ a_dst,
        float* __restrict__ asrc, float* __restrict__ adst, int n)
{
    int g = blockIdx.x * 4 + (threadIdx.x >> 6);
    int lane = threadIdx.x & 63;
    int node = g >> 2, head = g & 3;
    if (node >= n) return;
    const float* hp = h + (size_t)node * FDIM + head * HIDC;
    float v0 = hp[lane], v1 = hp[lane + 64];
    const float* as = a_src + head * HIDC;
    const float* ad = a_dst + head * HIDC;
    float s = v0 * as[lane] + v1 * as[lane + 64];
    float d = v0 * ad[lane] + v1 * ad[lane + 64];
#pragma unroll
    for (int off = 32; off > 0; off >>= 1){ s += __shfl_xor(s, off); d += __shfl_xor(d, off); }
    if (lane == 0){ asrc[node * 4 + head] = s; adst[node * 4 + head] = d; }
}

// ------------------------- CSR build ----------------------------------------
__global__ void edge_count(const int* __restrict__ dst, int e, int* __restrict__ cnt){
    int i = blockIdx.x * 256 + threadIdx.x;
    if (i >= e) return;
    int d = dst[i];
    if (d >= 0) atomicAdd(&cnt[d], 1);
}

__global__ __launch_bounds__(1024) void exscan(const int* __restrict__ cnt, int n, int* __restrict__ rs)
{
    __shared__ int wsum[16];
    __shared__ int woff[16];
    __shared__ int carry_s;
    int t = threadIdx.x;
    int lane = t & 63, wid = t >> 6;
    if (t == 0) carry_s = 0;
    __syncthreads();
    for (int base = 0; base < n; base += 1024){
        int i = base + t;
        int v = (i < n) ? cnt[i] : 0;
        int incl = v;
#pragma unroll
        for (int off = 1; off < 64; off <<= 1){
            int u = __shfl_up(incl, off);
            if (lane >= off) incl += u;
        }
        if (lane == 63) wsum[wid] = incl;
        __syncthreads();
        if (t == 0){
            int a = 0;
            for (int w = 0; w < 16; ++w){ woff[w] = a; a += wsum[w]; }
            wsum[0] = a;  // tile total
        }
        __syncthreads();
        int carry = carry_s;
        if (i < n) rs[i] = carry + woff[wid] + incl - v;
        __syncthreads();
        if (t == 0) carry_s = carry + wsum[0];
        __syncthreads();
    }
    if (t == 0) rs[n] = carry_s;
}

__global__ void edge_fill(const int* __restrict__ src, const int* __restrict__ dst, int e,
                          const int* __restrict__ rs, int* __restrict__ tmp, int* __restrict__ csr){
    int i = blockIdx.x * 256 + threadIdx.x;
    if (i >= e) return;
    int d = dst[i];
    if (d < 0) return;
    int pos = atomicAdd(&tmp[d], 1);
    csr[rs[d] + pos] = src[i];
}

// -------- GAT softmax + aggregate, one wave per (node, head) ----------------
__global__ __launch_bounds__(256) void gat_aggregate(const float* __restrict__ h,
        const float* __restrict__ asrc, const float* __restrict__ adst,
        const int* __restrict__ rs, const int* __restrict__ csr,
        const float* __restrict__ bias, float* __restrict__ out, int n)
{
    int g = blockIdx.x * 4 + (threadIdx.x >> 6);
    int lane = threadIdx.x & 63;
    int node = g >> 2, head = g & 3;
    if (node >= n) return;
    int e0 = rs[node], e1 = rs[node + 1];
    float adn  = adst[node * 4 + head];
    float slog = leaky(asrc[node * 4 + head] + adn);
    // max
    float mx = slog;
    for (int j = e0 + lane; j < e1; j += 64){
        int s = csr[j];
        mx = fmaxf(mx, leaky(asrc[s * 4 + head] + adn));
    }
#pragma unroll
    for (int off = 32; off > 0; off >>= 1) mx = fmaxf(mx, __shfl_xor(mx, off));
    // denom
    float lsum = 0.f;
    for (int j = e0 + lane; j < e1; j += 64){
        int s = csr[j];
        lsum += expf(leaky(asrc[s * 4 + head] + adn) - mx);
    }
#pragma unroll
    for (int off = 32; off > 0; off >>= 1) lsum += __shfl_xor(lsum, off);
    float es  = expf(slog - mx);
    float inv = 1.f / (lsum + es);
    // aggregate (all lanes cooperate per edge; 2 features/lane)
    int fb = head * HIDC;
    const float* hn = h + (size_t)node * FDIM + fb;
    float aself = es * inv;
    float acc0 = aself * hn[lane];
    float acc1 = aself * hn[lane + 64];
    for (int j = e0; j < e1; ++j){
        int s = csr[j];
        float al = expf(leaky(asrc[s * 4 + head] + adn) - mx) * inv;
        const float* hs = h + (size_t)s * FDIM + fb;
        acc0 += al * hs[lane];
        acc1 += al * hs[lane + 64];
    }
    out[(size_t)node * FDIM + fb + lane]      = elu(acc0 + bias[fb + lane]);
    out[(size_t)node * FDIM + fb + 64 + lane] = elu(acc1 + bias[fb + 64 + lane]);
}

// ------------------------- pooling ------------------------------------------
__global__ __launch_bounds__(512) void pw_norm(const float* __restrict__ w, float* __restrict__ invn){
    __shared__ float red[8];
    int t = threadIdx.x;
    float s = w[t] * w[t];
#pragma unroll
    for (int off = 32; off > 0; off >>= 1) s += __shfl_xor(s, off);
    if ((t & 63) == 0) red[t >> 6] = s;
    __syncthreads();
    if (t == 0){
        float a = 0;
        for (int i = 0; i < 8; ++i) a += red[i];
        *invn = rsqrtf(a);
    }
}

__global__ __launch_bounds__(256) void pool_score(const float* __restrict__ x, const float* __restrict__ w,
        const float* __restrict__ invn, float* __restrict__ score, int n){
    int g = blockIdx.x * 4 + (threadIdx.x >> 6);
    int lane = threadIdx.x & 63;
    if (g >= n) return;
    const float* xp = x + (size_t)g * FDIM;
    float s = 0.f;
#pragma unroll
    for (int q = 0; q < 8; ++q) s += xp[q * 64 + lane] * w[q * 64 + lane];
#pragma unroll
    for (int off = 32; off > 0; off >>= 1) s += __shfl_xor(s, off);
    if (lane == 0) score[g] = tanhf(s * (*invn));
}

// exact k-th threshold by 4x 8-bit radix passes; sel[0]=thresh key, sel[1]=#ties to keep
__global__ __launch_bounds__(256) void radix_select(const float* __restrict__ score, int n, int k,
                                                    unsigned* __restrict__ sel){
    __shared__ unsigned hist[256];
    __shared__ unsigned s_prefix, s_rem;
    int t = threadIdx.x;
    if (t == 0){ s_prefix = 0u; s_rem = (unsigned)k; }
    __syncthreads();
    for (int pass = 3; pass >= 0; --pass){
        hist[t] = 0u;
        __syncthreads();
        unsigned shift = (unsigned)pass * 8u;
        unsigned pmask = (pass == 3) ? 0u : (0xFFFFFFFFu << (shift + 8u));
        unsigned pref = s_prefix;
        for (int i = t; i < n; i += 256){
            unsigned key = ordkey(score[i]);
            if ((key & pmask) == pref) atomicAdd(&hist[(key >> shift) & 255u], 1u);
        }
        __syncthreads();
        if (t == 0){
            unsigned rem = s_rem, acc = 0, d = 255;
            for (;;){
                unsigned c = hist[d];
                if (acc + c >= rem) break;
                acc += c;
                if (d == 0) break;
                --d;
            }
            s_prefix = pref | (d << shift);
            s_rem = rem - acc;
        }
        __syncthreads();
    }
    if (t == 0){ sel[0] = s_prefix; sel[1] = s_rem; }
}

// sel[2]=tie ticket, sel[3]=kept counter (both pre-zeroed)
__global__ void pool_compact(const float* __restrict__ score, int n,
                             unsigned* __restrict__ sel, int* __restrict__ remap,
                             int* __restrict__ oldidx){
    int i = blockIdx.x * 256 + threadIdx.x;
    if (i >= n) return;
    unsigned T = sel[0], ties = sel[1];
    unsigned key = ordkey(score[i]);
    int keep = 0;
    if (key > T) keep = 1;
    else if (key == T){
        unsigned tk = atomicAdd(&sel[2], 1u);
        if (tk < ties) keep = 1;
    }
    if (keep){
        int pos = (int)atomicAdd(&sel[3], 1u);
        remap[i] = pos;
        oldidx[pos] = i;
    } else remap[i] = -1;
}

__global__ __launch_bounds__(256) void pool_gather(const float* __restrict__ x, const int* __restrict__ oldidx,
        const float* __restrict__ score, float* __restrict__ xn, int k){
    int j = blockIdx.x;
    if (j >= k) return;
    int old = oldidx[j];
    float v = score[old];
    for (int f = threadIdx.x; f < FDIM; f += 256)
        xn[(size_t)j * FDIM + f] = x[(size_t)old * FDIM + f] * v;
}

__global__ void edge_remap(const int* __restrict__ src, const int* __restrict__ dst,
                           const int* __restrict__ remap, int* __restrict__ src2,
                           int* __restrict__ dst2, int e){
    int i = blockIdx.x * 256 + threadIdx.x;
    if (i >= e) return;
    int s = remap[src[i]], d = remap[dst[i]];
    if (s >= 0 && d >= 0){ src2[i] = s; dst2[i] = d; }
    else { src2[i] = -1; dst2[i] = -1; }
}

// ----------------- readout --------------------------------------------------
__global__ __launch_bounds__(512) void final_reduce(const float* __restrict__ x, const int* __restrict__ oldidx,
        const float* __restrict__ score, int k, float* __restrict__ gsum){
    int t = threadIdx.x; // 512
    float a = 0.f;
    for (int j = blockIdx.x; j < k; j += gridDim.x){
        int o = oldidx[j];
        a += x[(size_t)o * FDIM + t] * score[o];
    }
    atomicAdd(&gsum[t], a);
}

__global__ __launch_bounds__(640) void final_gemm(const float* __restrict__ g, const float* __restrict__ Wl,
        const float* __restrict__ bl, float* __restrict__ out){
    int w = threadIdx.x >> 6;   // 0..9
    int lane = threadIdx.x & 63;
    float s = 0.f;
    for (int f = lane; f < FDIM; f += 64) s += g[f] * Wl[f * 10 + w];
#pragma unroll
    for (int off = 32; off > 0; off >>= 1) s += __shfl_xor(s, off);
    if (lane == 0) out[w] = s * (1.0f / K2_KEEP) + bl[w];
}

extern "C" void kernel_launch(void* const* d_in, const int* in_sizes, int n_in,
                              void* d_out, int out_size, void* d_ws, size_t ws_size,
                              hipStream_t stream)
{
    (void)in_sizes; (void)n_in; (void)out_size; (void)ws_size;
    const float* x   = (const float*)d_in[0];
    const int*   ei  = (const int*)  d_in[1];
    const float* W1  = (const float*)d_in[3];
    const float* as1 = (const float*)d_in[4];
    const float* ad1 = (const float*)d_in[5];
    const float* b1  = (const float*)d_in[6];
    const float* pw1 = (const float*)d_in[7];
    const float* W2  = (const float*)d_in[8];
    const float* as2 = (const float*)d_in[9];
    const float* ad2 = (const float*)d_in[10];
    const float* b2  = (const float*)d_in[11];
    const float* pw2 = (const float*)d_in[12];
    const float* Wl  = (const float*)d_in[13];
    const float* bl  = (const float*)d_in[14];
    const int* src1 = ei;
    const int* dst1 = ei + E_EDGES;

    char* wsb = (char*)d_ws;
    size_t off = 0;
    auto alloc = [&](size_t bytes) -> char* {
        char* p = wsb + off;
        off += (bytes + 255) & ~(size_t)255;
        return p;
    };
    float* h1   = (float*)alloc((size_t)N_NODES * FDIM * 4);  // reused: h2 + out2
    float* out1 = (float*)alloc((size_t)N_NODES * FDIM * 4);
    float* x2   = (float*)alloc((size_t)K1_KEEP * FDIM * 4);
    float* asrc = (float*)alloc((size_t)N_NODES * NHEAD * 4);
    float* adst = (float*)alloc((size_t)N_NODES * NHEAD * 4);
    float* score= (float*)alloc((size_t)N_NODES * 4);
    float* invn = (float*)alloc(4);
    unsigned* sel = (unsigned*)alloc(16);
    int* cnt  = (int*)alloc((size_t)(N_NODES + 1) * 4);
    int* rsx  = (int*)alloc((size_t)(N_NODES + 1) * 4);
    int* tmp  = (int*)alloc((size_t)N_NODES * 4);
    int* csr  = (int*)alloc((size_t)E_EDGES * 4);
    int* src2 = (int*)alloc((size_t)E_EDGES * 4);
    int* dst2 = (int*)alloc((size_t)E_EDGES * 4);
    int* remap= (int*)alloc((size_t)N_NODES * 4);
    int* oldi = (int*)alloc((size_t)K1_KEEP * 4);
    float* gsum = (float*)alloc(512 * 4);
    float* h2   = h1;                            // layer-2 aliases into h1 region
    float* out2 = h1 + (size_t)K1_KEEP * FDIM;   // N*F == 2*K1*F, fits exactly

    // ---- layer 1 (GAT on N nodes, E edges + self loops) ----
    gemm_rm<64><<<(N_NODES + 31) / 32, 256, 0, stream>>>(x, W1, h1, N_NODES);
    attn_scores<<<N_NODES, 256, 0, stream>>>(h1, as1, ad1, asrc, adst, N_NODES);
    hipMemsetAsync(cnt, 0, (size_t)N_NODES * 4, stream);
    edge_count<<<(E_EDGES + 255) / 256, 256, 0, stream>>>(dst1, E_EDGES, cnt);
    exscan<<<1, 1024, 0, stream>>>(cnt, N_NODES, rsx);
    hipMemsetAsync(tmp, 0, (size_t)N_NODES * 4, stream);
    edge_fill<<<(E_EDGES + 255) / 256, 256, 0, stream>>>(src1, dst1, E_EDGES, rsx, tmp, csr);
    gat_aggregate<<<N_NODES, 256, 0, stream>>>(h1, asrc, adst, rsx, csr, b1, out1, N_NODES);

    // ---- pool 1 (keep K1) ----
    pw_norm<<<1, 512, 0, stream>>>(pw1, invn);
    pool_score<<<(N_NODES + 3) / 4, 256, 0, stream>>>(out1, pw1, invn, score, N_NODES);
    hipMemsetAsync(sel, 0, 16, stream);
    radix_select<<<1, 256, 0, stream>>>(score, N_NODES, K1_KEEP, sel);
    pool_compact<<<(N_NODES + 255) / 256, 256, 0, stream>>>(score, N_NODES, sel, remap, oldi);
    pool_gather<<<K1_KEEP, 256, 0, stream>>>(out1, oldi, score, x2, K1_KEEP);
    edge_remap<<<(E_EDGES + 255) / 256, 256, 0, stream>>>(src1, dst1, remap, src2, dst2, E_EDGES);

    // ---- layer 2 (GAT on K1 nodes, masked edges + self loops) ----
    gemm_rm<512><<<(K1_KEEP + 31) / 32, 256, 0, stream>>>(x2, W2, h2, K1_KEEP);
    attn_scores<<<K1_KEEP, 256, 0, stream>>>(h2, as2, ad2, asrc, adst, K1_KEEP);
    hipMemsetAsync(cnt, 0, (size_t)K1_KEEP * 4, stream);
    edge_count<<<(E_EDGES + 255) / 256, 256, 0, stream>>>(dst2, E_EDGES, cnt);
    exscan<<<1, 1024, 0, stream>>>(cnt, K1_KEEP, rsx);
    hipMemsetAsync(tmp, 0, (size_t)K1_KEEP * 4, stream);
    edge_fill<<<(E_EDGES + 255) / 256, 256, 0, stream>>>(src2, dst2, E_EDGES, rsx, tmp, csr);
    gat_aggregate<<<K1_KEEP, 256, 0, stream>>>(h2, asrc, adst, rsx, csr, b2, out2, K1_KEEP);

    // ---- pool 2 (keep K2) + readout ----
    pw_norm<<<1, 512, 0, stream>>>(pw2, invn);
    pool_score<<<(K1_KEEP + 3) / 4, 256, 0, stream>>>(out2, pw2, invn, score, K1_KEEP);
    hipMemsetAsync(sel, 0, 16, stream);
    radix_select<<<1, 256, 0, stream>>>(score, K1_KEEP, K2_KEEP, sel);
    pool_compact<<<(K1_KEEP + 255) / 256, 256, 0, stream>>>(score, K1_KEEP, sel, remap, oldi);
    hipMemsetAsync(gsum, 0, 512 * 4, stream);
    final_reduce<<<64, 512, 0, stream>>>(out2, oldi, score, K2_KEEP, gsum);
    final_gemm<<<1, 640, 0, stream>>>(gsum, Wl, bl, (float*)d_out);
}

// Round 2
// 608.146 us; speedup vs baseline: 1.2733x; 1.2733x over previous
//
#include <hip/hip_runtime.h>
#include <math.h>

#define N_NODES 20000
#define E_EDGES 200000
#define K1_KEEP 10000
#define K2_KEEP 5000
#define HIDC 128
#define NHEAD 4
#define FDIM 512   // NHEAD*HIDC
#define NEG 0.2f

__device__ __forceinline__ float leaky(float x){ return x > 0.f ? x : NEG * x; }
__device__ __forceinline__ float elu(float x){ return x > 0.f ? x : expm1f(x); }
// monotone float->uint key (ascending)
__device__ __forceinline__ unsigned ordkey(float f){
    unsigned u = __float_as_uint(f);
    return (u & 0x80000000u) ? ~u : (u | 0x80000000u);
}

// ---------------- GEMM: out[n x 512] = A[n x K] @ W[K x 512] ----------------
// 64x128 tile per 256-thread block, KC=32, A+W staged in LDS, 4x8 per thread.
template<int K>
__global__ __launch_bounds__(256) void gemm_tile(const float* __restrict__ A,
                                                 const float* __restrict__ W,
                                                 float* __restrict__ out, int n)
{
    __shared__ float At[32][68];   // transposed A tile, stride 68 (16B-aligned rows)
    __shared__ float Wt[32][128];
    int t = threadIdx.x;
    int row0 = (blockIdx.x >> 2) * 64;
    int col0 = (blockIdx.x & 3) * 128;
    int tr = t >> 4;       // 0..15 -> rows 4*tr..4*tr+3
    int tc = t & 15;       // 0..15 -> cols 8*tc..8*tc+7
    float acc[4][8];
#pragma unroll
    for (int r = 0; r < 4; ++r)
#pragma unroll
        for (int c = 0; c < 8; ++c) acc[r][c] = 0.f;

    for (int kc = 0; kc < K; kc += 32){
        // stage A: 64 rows x 32 k (transposed into At)
#pragma unroll
        for (int i = 0; i < 2; ++i){
            int s = t + i * 256;
            int r = s >> 3, kq = s & 7;
            int gr = row0 + r;
            float4 v = make_float4(0.f, 0.f, 0.f, 0.f);
            if (gr < n) v = *reinterpret_cast<const float4*>(&A[(size_t)gr * K + kc + kq * 4]);
            At[kq * 4 + 0][r] = v.x;
            At[kq * 4 + 1][r] = v.y;
            At[kq * 4 + 2][r] = v.z;
            At[kq * 4 + 3][r] = v.w;
        }
        // stage W: 32 k x 128 cols
#pragma unroll
        for (int i = 0; i < 4; ++i){
            int s = t + i * 256;
            int k = s >> 5, c4 = s & 31;
            *reinterpret_cast<float4*>(&Wt[k][c4 * 4]) =
                *reinterpret_cast<const float4*>(&W[(size_t)(kc + k) * 512 + col0 + c4 * 4]);
        }
        __syncthreads();
#pragma unroll 4
        for (int kk = 0; kk < 32; ++kk){
            float4 a  = *reinterpret_cast<const float4*>(&At[kk][tr * 4]);
            float4 w0 = *reinterpret_cast<const float4*>(&Wt[kk][tc * 8]);
            float4 w1 = *reinterpret_cast<const float4*>(&Wt[kk][tc * 8 + 4]);
            float af[4] = {a.x, a.y, a.z, a.w};
            float wf[8] = {w0.x, w0.y, w0.z, w0.w, w1.x, w1.y, w1.z, w1.w};
#pragma unroll
            for (int r = 0; r < 4; ++r)
#pragma unroll
                for (int c = 0; c < 8; ++c) acc[r][c] += af[r] * wf[c];
        }
        __syncthreads();
    }
#pragma unroll
    for (int r = 0; r < 4; ++r){
        int gr = row0 + 4 * tr + r;
        if (gr < n){
            float4* o = reinterpret_cast<float4*>(&out[(size_t)gr * 512 + col0 + tc * 8]);
            o[0] = make_float4(acc[r][0], acc[r][1], acc[r][2], acc[r][3]);
            o[1] = make_float4(acc[r][4], acc[r][5], acc[r][6], acc[r][7]);
        }
    }
}

// ------------- attention scores: asrc[n][h], adst[n][h] ---------------------
__global__ __launch_bounds__(256) void attn_scores(const float* __restrict__ h,
        const float* __restrict__ a_src, const float* __restrict__ a_dst,
        float* __restrict__ asrc, float* __restrict__ adst, int n)
{
    int g = blockIdx.x * 4 + (threadIdx.x >> 6);
    int lane = threadIdx.x & 63;
    int node = g >> 2, head = g & 3;
    if (node >= n) return;
    const float* hp = h + (size_t)node * FDIM + head * HIDC;
    float v0 = hp[lane], v1 = hp[lane + 64];
    const float* as = a_src + head * HIDC;
    const float* ad = a_dst + head * HIDC;
    float s = v0 * as[lane] + v1 * as[lane + 64];
    float d = v0 * ad[lane] + v1 * ad[lane + 64];
#pragma unroll
    for (int off = 32; off > 0; off >>= 1){ s += __shfl_xor(s, off); d += __shfl_xor(d, off); }
    if (lane == 0){ asrc[node * 4 + head] = s; adst[node * 4 + head] = d; }
}

// ------------------------- CSR build ----------------------------------------
__global__ void edge_count(const int* __restrict__ dst, int e, int* __restrict__ cnt){
    int i = blockIdx.x * 256 + threadIdx.x;
    if (i >= e) return;
    int d = dst[i];
    if (d >= 0) atomicAdd(&cnt[d], 1);
}

__global__ __launch_bounds__(1024) void exscan(const int* __restrict__ cnt, int n, int* __restrict__ rs)
{
    __shared__ int wsum[16];
    __shared__ int woff[16];
    __shared__ int carry_s;
    int t = threadIdx.x;
    int lane = t & 63, wid = t >> 6;
    if (t == 0) carry_s = 0;
    __syncthreads();
    for (int base = 0; base < n; base += 1024){
        int i = base + t;
        int v = (i < n) ? cnt[i] : 0;
        int incl = v;
#pragma unroll
        for (int off = 1; off < 64; off <<= 1){
            int u = __shfl_up(incl, off);
            if (lane >= off) incl += u;
        }
        if (lane == 63) wsum[wid] = incl;
        __syncthreads();
        if (t == 0){
            int a = 0;
            for (int w = 0; w < 16; ++w){ woff[w] = a; a += wsum[w]; }
            wsum[0] = a;  // tile total
        }
        __syncthreads();
        int carry = carry_s;
        if (i < n) rs[i] = carry + woff[wid] + incl - v;
        __syncthreads();
        if (t == 0) carry_s = carry + wsum[0];
        __syncthreads();
    }
    if (t == 0) rs[n] = carry_s;
}

__global__ void edge_fill(const int* __restrict__ src, const int* __restrict__ dst, int e,
                          const int* __restrict__ rs, int* __restrict__ tmp, int* __restrict__ csr){
    int i = blockIdx.x * 256 + threadIdx.x;
    if (i >= e) return;
    int d = dst[i];
    if (d < 0) return;
    int pos = atomicAdd(&tmp[d], 1);
    csr[rs[d] + pos] = src[i];
}

// -------- GAT softmax + aggregate, one wave per (node, head) ----------------
__global__ __launch_bounds__(256) void gat_aggregate(const float* __restrict__ h,
        const float* __restrict__ asrc, const float* __restrict__ adst,
        const int* __restrict__ rs, const int* __restrict__ csr,
        const float* __restrict__ bias, float* __restrict__ out, int n)
{
    int g = blockIdx.x * 4 + (threadIdx.x >> 6);
    int lane = threadIdx.x & 63;
    int node = g >> 2, head = g & 3;
    if (node >= n) return;
    int e0 = rs[node], e1 = rs[node + 1];
    float adn  = adst[node * 4 + head];
    float slog = leaky(asrc[node * 4 + head] + adn);
    float mx = slog;
    for (int j = e0 + lane; j < e1; j += 64){
        int s = csr[j];
        mx = fmaxf(mx, leaky(asrc[s * 4 + head] + adn));
    }
#pragma unroll
    for (int off = 32; off > 0; off >>= 1) mx = fmaxf(mx, __shfl_xor(mx, off));
    float lsum = 0.f;
    for (int j = e0 + lane; j < e1; j += 64){
        int s = csr[j];
        lsum += expf(leaky(asrc[s * 4 + head] + adn) - mx);
    }
#pragma unroll
    for (int off = 32; off > 0; off >>= 1) lsum += __shfl_xor(lsum, off);
    float es  = expf(slog - mx);
    float inv = 1.f / (lsum + es);
    int fb = head * HIDC;
    const float* hn = h + (size_t)node * FDIM + fb;
    float aself = es * inv;
    float acc0 = aself * hn[lane];
    float acc1 = aself * hn[lane + 64];
    for (int j = e0; j < e1; ++j){
        int s = csr[j];
        float al = expf(leaky(asrc[s * 4 + head] + adn) - mx) * inv;
        const float* hs = h + (size_t)s * FDIM + fb;
        acc0 += al * hs[lane];
        acc1 += al * hs[lane + 64];
    }
    out[(size_t)node * FDIM + fb + lane]      = elu(acc0 + bias[fb + lane]);
    out[(size_t)node * FDIM + fb + 64 + lane] = elu(acc1 + bias[fb + 64 + lane]);
}

// ------------------------- pooling ------------------------------------------
__global__ __launch_bounds__(512) void pw_norm(const float* __restrict__ w, float* __restrict__ invn){
    __shared__ float red[8];
    int t = threadIdx.x;
    float s = w[t] * w[t];
#pragma unroll
    for (int off = 32; off > 0; off >>= 1) s += __shfl_xor(s, off);
    if ((t & 63) == 0) red[t >> 6] = s;
    __syncthreads();
    if (t == 0){
        float a = 0;
        for (int i = 0; i < 8; ++i) a += red[i];
        *invn = rsqrtf(a);
    }
}

__global__ __launch_bounds__(256) void pool_score(const float* __restrict__ x, const float* __restrict__ w,
        const float* __restrict__ invn, float* __restrict__ score, int n){
    int g = blockIdx.x * 4 + (threadIdx.x >> 6);
    int lane = threadIdx.x & 63;
    if (g >= n) return;
    const float* xp = x + (size_t)g * FDIM;
    float s = 0.f;
#pragma unroll
    for (int q = 0; q < 8; ++q) s += xp[q * 64 + lane] * w[q * 64 + lane];
#pragma unroll
    for (int off = 32; off > 0; off >>= 1) s += __shfl_xor(s, off);
    if (lane == 0) score[g] = tanhf(s * (*invn));
}

// exact k-th threshold by 4x 8-bit radix passes; sel[0]=thresh key, sel[1]=#ties to keep
__global__ __launch_bounds__(1024) void radix_select(const float* __restrict__ score, int n, int k,
                                                     unsigned* __restrict__ sel){
    __shared__ unsigned hist[256];
    __shared__ unsigned s_prefix, s_rem;
    int t = threadIdx.x;
    if (t == 0){ s_prefix = 0u; s_rem = (unsigned)k; }
    if (t < 256) hist[t] = 0u;
    __syncthreads();
    for (int pass = 3; pass >= 0; --pass){
        unsigned shift = (unsigned)pass * 8u;
        unsigned pmask = (pass == 3) ? 0u : (0xFFFFFFFFu << (shift + 8u));
        unsigned pref = s_prefix;
        for (int i = t; i < n; i += 1024){
            unsigned key = ordkey(score[i]);
            if ((key & pmask) == pref) atomicAdd(&hist[(key >> shift) & 255u], 1u);
        }
        __syncthreads();
        if (t == 0){
            unsigned rem = s_rem, acc = 0, d = 255;
            for (;;){
                unsigned c = hist[d];
                if (acc + c >= rem) break;
                acc += c;
                if (d == 0) break;
                --d;
            }
            s_prefix = pref | (d << shift);
            s_rem = rem - acc;
        }
        __syncthreads();
        if (t < 256) hist[t] = 0u;
        __syncthreads();
    }
    if (t == 0){ sel[0] = s_prefix; sel[1] = s_rem; }
}

// sel[2]=tie ticket, sel[3]=kept counter (both pre-zeroed)
__global__ void pool_compact(const float* __restrict__ score, int n,
                             unsigned* __restrict__ sel, int* __restrict__ remap,
                             int* __restrict__ oldidx){
    int i = blockIdx.x * 256 + threadIdx.x;
    if (i >= n) return;
    unsigned T = sel[0], ties = sel[1];
    unsigned key = ordkey(score[i]);
    int keep = 0;
    if (key > T) keep = 1;
    else if (key == T){
        unsigned tk = atomicAdd(&sel[2], 1u);
        if (tk < ties) keep = 1;
    }
    if (keep){
        int pos = (int)atomicAdd(&sel[3], 1u);
        remap[i] = pos;
        oldidx[pos] = i;
    } else remap[i] = -1;
}

__global__ __launch_bounds__(256) void pool_gather(const float* __restrict__ x, const int* __restrict__ oldidx,
        const float* __restrict__ score, float* __restrict__ xn, int k){
    int j = blockIdx.x;
    if (j >= k) return;
    int old = oldidx[j];
    float v = score[old];
    for (int f = threadIdx.x; f < FDIM; f += 256)
        xn[(size_t)j * FDIM + f] = x[(size_t)old * FDIM + f] * v;
}

__global__ void edge_remap(const int* __restrict__ src, const int* __restrict__ dst,
                           const int* __restrict__ remap, int* __restrict__ src2,
                           int* __restrict__ dst2, int e){
    int i = blockIdx.x * 256 + threadIdx.x;
    if (i >= e) return;
    int s = remap[src[i]], d = remap[dst[i]];
    if (s >= 0 && d >= 0){ src2[i] = s; dst2[i] = d; }
    else { src2[i] = -1; dst2[i] = -1; }
}

// ----------------- readout --------------------------------------------------
__global__ __launch_bounds__(512) void final_reduce(const float* __restrict__ x, const int* __restrict__ oldidx,
        const float* __restrict__ score, int k, float* __restrict__ gsum){
    int t = threadIdx.x; // 512
    float a = 0.f;
    for (int j = blockIdx.x; j < k; j += gridDim.x){
        int o = oldidx[j];
        a += x[(size_t)o * FDIM + t] * score[o];
    }
    atomicAdd(&gsum[t], a);
}

__global__ __launch_bounds__(640) void final_gemm(const float* __restrict__ g, const float* __restrict__ Wl,
        const float* __restrict__ bl, float* __restrict__ out){
    int w = threadIdx.x >> 6;   // 0..9
    int lane = threadIdx.x & 63;
    float s = 0.f;
    for (int f = lane; f < FDIM; f += 64) s += g[f] * Wl[f * 10 + w];
#pragma unroll
    for (int off = 32; off > 0; off >>= 1) s += __shfl_xor(s, off);
    if (lane == 0) out[w] = s * (1.0f / K2_KEEP) + bl[w];
}

extern "C" void kernel_launch(void* const* d_in, const int* in_sizes, int n_in,
                              void* d_out, int out_size, void* d_ws, size_t ws_size,
                              hipStream_t stream)
{
    (void)in_sizes; (void)n_in; (void)out_size; (void)ws_size;
    const float* x   = (const float*)d_in[0];
    const int*   ei  = (const int*)  d_in[1];
    const float* W1  = (const float*)d_in[3];
    const float* as1 = (const float*)d_in[4];
    const float* ad1 = (const float*)d_in[5];
    const float* b1  = (const float*)d_in[6];
    const float* pw1 = (const float*)d_in[7];
    const float* W2  = (const float*)d_in[8];
    const float* as2 = (const float*)d_in[9];
    const float* ad2 = (const float*)d_in[10];
    const float* b2  = (const float*)d_in[11];
    const float* pw2 = (const float*)d_in[12];
    const float* Wl  = (const float*)d_in[13];
    const float* bl  = (const float*)d_in[14];
    const int* src1 = ei;
    const int* dst1 = ei + E_EDGES;

    char* wsb = (char*)d_ws;
    size_t off = 0;
    auto alloc = [&](size_t bytes) -> char* {
        char* p = wsb + off;
        off += (bytes + 255) & ~(size_t)255;
        return p;
    };
    float* h1   = (float*)alloc((size_t)N_NODES * FDIM * 4);  // reused: h2 + out2
    float* out1 = (float*)alloc((size_t)N_NODES * FDIM * 4);
    float* x2   = (float*)alloc((size_t)K1_KEEP * FDIM * 4);
    float* asrc = (float*)alloc((size_t)N_NODES * NHEAD * 4);
    float* adst = (float*)alloc((size_t)N_NODES * NHEAD * 4);
    float* score= (float*)alloc((size_t)N_NODES * 4);
    float* invn = (float*)alloc(4);
    unsigned* sel = (unsigned*)alloc(16);
    int* cnt  = (int*)alloc((size_t)(N_NODES + 1) * 4);
    int* rsx  = (int*)alloc((size_t)(N_NODES + 1) * 4);
    int* tmp  = (int*)alloc((size_t)N_NODES * 4);
    int* csr  = (int*)alloc((size_t)E_EDGES * 4);
    int* src2 = (int*)alloc((size_t)E_EDGES * 4);
    int* dst2 = (int*)alloc((size_t)E_EDGES * 4);
    int* remap= (int*)alloc((size_t)N_NODES * 4);
    int* oldi = (int*)alloc((size_t)K1_KEEP * 4);
    float* gsum = (float*)alloc(512 * 4);
    float* h2   = h1;                            // layer-2 aliases into h1 region
    float* out2 = h1 + (size_t)K1_KEEP * FDIM;   // N*F == 2*K1*F, fits exactly

    // ---- layer 1 (GAT on N nodes, E edges + self loops) ----
    int gx1 = (N_NODES + 63) / 64;
    gemm_tile<64><<<gx1 * 4, 256, 0, stream>>>(x, W1, h1, N_NODES);
    attn_scores<<<N_NODES, 256, 0, stream>>>(h1, as1, ad1, asrc, adst, N_NODES);
    hipMemsetAsync(cnt, 0, (size_t)N_NODES * 4, stream);
    edge_count<<<(E_EDGES + 255) / 256, 256, 0, stream>>>(dst1, E_EDGES, cnt);
    exscan<<<1, 1024, 0, stream>>>(cnt, N_NODES, rsx);
    hipMemsetAsync(tmp, 0, (size_t)N_NODES * 4, stream);
    edge_fill<<<(E_EDGES + 255) / 256, 256, 0, stream>>>(src1, dst1, E_EDGES, rsx, tmp, csr);
    gat_aggregate<<<N_NODES, 256, 0, stream>>>(h1, asrc, adst, rsx, csr, b1, out1, N_NODES);

    // ---- pool 1 (keep K1) ----
    pw_norm<<<1, 512, 0, stream>>>(pw1, invn);
    pool_score<<<(N_NODES + 3) / 4, 256, 0, stream>>>(out1, pw1, invn, score, N_NODES);
    hipMemsetAsync(sel, 0, 16, stream);
    radix_select<<<1, 1024, 0, stream>>>(score, N_NODES, K1_KEEP, sel);
    pool_compact<<<(N_NODES + 255) / 256, 256, 0, stream>>>(score, N_NODES, sel, remap, oldi);
    pool_gather<<<K1_KEEP, 256, 0, stream>>>(out1, oldi, score, x2, K1_KEEP);
    edge_remap<<<(E_EDGES + 255) / 256, 256, 0, stream>>>(src1, dst1, remap, src2, dst2, E_EDGES);

    // ---- layer 2 (GAT on K1 nodes, masked edges + self loops) ----
    int gx2 = (K1_KEEP + 63) / 64;
    gemm_tile<512><<<gx2 * 4, 256, 0, stream>>>(x2, W2, h2, K1_KEEP);
    attn_scores<<<K1_KEEP, 256, 0, stream>>>(h2, as2, ad2, asrc, adst, K1_KEEP);
    hipMemsetAsync(cnt, 0, (size_t)K1_KEEP * 4, stream);
    edge_count<<<(E_EDGES + 255) / 256, 256, 0, stream>>>(dst2, E_EDGES, cnt);
    exscan<<<1, 1024, 0, stream>>>(cnt, K1_KEEP, rsx);
    hipMemsetAsync(tmp, 0, (size_t)K1_KEEP * 4, stream);
    edge_fill<<<(E_EDGES + 255) / 256, 256, 0, stream>>>(src2, dst2, E_EDGES, rsx, tmp, csr);
    gat_aggregate<<<K1_KEEP, 256, 0, stream>>>(h2, asrc, adst, rsx, csr, b2, out2, K1_KEEP);

    // ---- pool 2 (keep K2) + readout ----
    pw_norm<<<1, 512, 0, stream>>>(pw2, invn);
    pool_score<<<(K1_KEEP + 3) / 4, 256, 0, stream>>>(out2, pw2, invn, score, K1_KEEP);
    hipMemsetAsync(sel, 0, 16, stream);
    radix_select<<<1, 1024, 0, stream>>>(score, K1_KEEP, K2_KEEP, sel);
    pool_compact<<<(K1_KEEP + 255) / 256, 256, 0, stream>>>(score, K1_KEEP, sel, remap, oldi);
    hipMemsetAsync(gsum, 0, 512 * 4, stream);
    final_reduce<<<64, 512, 0, stream>>>(out2, oldi, score, K2_KEEP, gsum);
    final_gemm<<<1, 640, 0, stream>>>(gsum, Wl, bl, (float*)d_out);
}

// Round 3
// 591.380 us; speedup vs baseline: 1.3094x; 1.0283x over previous
//
#include <hip/hip_runtime.h>
#include <math.h>

#define N_NODES 20000
#define E_EDGES 200000
#define K1_KEEP 10000
#define K2_KEEP 5000
#define HIDC 128
#define NHEAD 4
#define FDIM 512   // NHEAD*HIDC
#define NEG 0.2f

__device__ __forceinline__ float leaky(float x){ return x > 0.f ? x : NEG * x; }
__device__ __forceinline__ float elu(float x){ return x > 0.f ? x : expm1f(x); }
// monotone float->uint key (ascending)
__device__ __forceinline__ unsigned ordkey(float f){
    unsigned u = __float_as_uint(f);
    return (u & 0x80000000u) ? ~u : (u | 0x80000000u);
}

// ---------------- GEMM: out[n x 512] = A[n x K] @ W[K x 512] ----------------
// 64x128 tile per 256-thread block, KC=32, A+W staged in LDS, 4x8 per thread.
template<int K>
__global__ __launch_bounds__(256) void gemm_tile(const float* __restrict__ A,
                                                 const float* __restrict__ W,
                                                 float* __restrict__ out, int n)
{
    __shared__ float At[32][68];   // transposed A tile, stride 68 (16B-aligned rows)
    __shared__ float Wt[32][128];
    int t = threadIdx.x;
    int row0 = (blockIdx.x >> 2) * 64;
    int col0 = (blockIdx.x & 3) * 128;
    int tr = t >> 4;       // 0..15 -> rows 4*tr..4*tr+3
    int tc = t & 15;       // 0..15 -> cols 8*tc..8*tc+7
    float acc[4][8];
#pragma unroll
    for (int r = 0; r < 4; ++r)
#pragma unroll
        for (int c = 0; c < 8; ++c) acc[r][c] = 0.f;

    for (int kc = 0; kc < K; kc += 32){
#pragma unroll
        for (int i = 0; i < 2; ++i){
            int s = t + i * 256;
            int r = s >> 3, kq = s & 7;
            int gr = row0 + r;
            float4 v = make_float4(0.f, 0.f, 0.f, 0.f);
            if (gr < n) v = *reinterpret_cast<const float4*>(&A[(size_t)gr * K + kc + kq * 4]);
            At[kq * 4 + 0][r] = v.x;
            At[kq * 4 + 1][r] = v.y;
            At[kq * 4 + 2][r] = v.z;
            At[kq * 4 + 3][r] = v.w;
        }
#pragma unroll
        for (int i = 0; i < 4; ++i){
            int s = t + i * 256;
            int k = s >> 5, c4 = s & 31;
            *reinterpret_cast<float4*>(&Wt[k][c4 * 4]) =
                *reinterpret_cast<const float4*>(&W[(size_t)(kc + k) * 512 + col0 + c4 * 4]);
        }
        __syncthreads();
#pragma unroll 4
        for (int kk = 0; kk < 32; ++kk){
            float4 a  = *reinterpret_cast<const float4*>(&At[kk][tr * 4]);
            float4 w0 = *reinterpret_cast<const float4*>(&Wt[kk][tc * 8]);
            float4 w1 = *reinterpret_cast<const float4*>(&Wt[kk][tc * 8 + 4]);
            float af[4] = {a.x, a.y, a.z, a.w};
            float wf[8] = {w0.x, w0.y, w0.z, w0.w, w1.x, w1.y, w1.z, w1.w};
#pragma unroll
            for (int r = 0; r < 4; ++r)
#pragma unroll
                for (int c = 0; c < 8; ++c) acc[r][c] += af[r] * wf[c];
        }
        __syncthreads();
    }
#pragma unroll
    for (int r = 0; r < 4; ++r){
        int gr = row0 + 4 * tr + r;
        if (gr < n){
            float4* o = reinterpret_cast<float4*>(&out[(size_t)gr * 512 + col0 + tc * 8]);
            o[0] = make_float4(acc[r][0], acc[r][1], acc[r][2], acc[r][3]);
            o[1] = make_float4(acc[r][4], acc[r][5], acc[r][6], acc[r][7]);
        }
    }
}

// ------------- attention scores: asrc[n][h], adst[n][h] ---------------------
__global__ __launch_bounds__(256) void attn_scores(const float* __restrict__ h,
        const float* __restrict__ a_src, const float* __restrict__ a_dst,
        float* __restrict__ asrc, float* __restrict__ adst, int n)
{
    int g = blockIdx.x * 4 + (threadIdx.x >> 6);
    int lane = threadIdx.x & 63;
    int node = g >> 2, head = g & 3;
    if (node >= n) return;
    const float* hp = h + (size_t)node * FDIM + head * HIDC;
    float v0 = hp[lane], v1 = hp[lane + 64];
    const float* as = a_src + head * HIDC;
    const float* ad = a_dst + head * HIDC;
    float s = v0 * as[lane] + v1 * as[lane + 64];
    float d = v0 * ad[lane] + v1 * ad[lane + 64];
#pragma unroll
    for (int off = 32; off > 0; off >>= 1){ s += __shfl_xor(s, off); d += __shfl_xor(d, off); }
    if (lane == 0){ asrc[node * 4 + head] = s; adst[node * 4 + head] = d; }
}

// ------------------------- CSR build ----------------------------------------
__global__ void edge_count(const int* __restrict__ dst, int e, int* __restrict__ cnt){
    int i = blockIdx.x * 256 + threadIdx.x;
    if (i >= e) return;
    int d = dst[i];
    if (d >= 0) atomicAdd(&cnt[d], 1);
}

__global__ __launch_bounds__(1024) void exscan(const int* __restrict__ cnt, int n, int* __restrict__ rs)
{
    __shared__ int wsum[16];
    __shared__ int woff[16];
    __shared__ int carry_s;
    int t = threadIdx.x;
    int lane = t & 63, wid = t >> 6;
    if (t == 0) carry_s = 0;
    __syncthreads();
    for (int base = 0; base < n; base += 1024){
        int i = base + t;
        int v = (i < n) ? cnt[i] : 0;
        int incl = v;
#pragma unroll
        for (int off = 1; off < 64; off <<= 1){
            int u = __shfl_up(incl, off);
            if (lane >= off) incl += u;
        }
        if (lane == 63) wsum[wid] = incl;
        __syncthreads();
        if (t == 0){
            int a = 0;
            for (int w = 0; w < 16; ++w){ woff[w] = a; a += wsum[w]; }
            wsum[0] = a;  // tile total
        }
        __syncthreads();
        int carry = carry_s;
        if (i < n) rs[i] = carry + woff[wid] + incl - v;
        __syncthreads();
        if (t == 0) carry_s = carry + wsum[0];
        __syncthreads();
    }
    if (t == 0) rs[n] = carry_s;
}

__global__ void edge_fill(const int* __restrict__ src, const int* __restrict__ dst, int e,
                          const int* __restrict__ rs, int* __restrict__ tmp, int* __restrict__ csr){
    int i = blockIdx.x * 256 + threadIdx.x;
    if (i >= e) return;
    int d = dst[i];
    if (d < 0) return;
    int pos = atomicAdd(&tmp[d], 1);
    csr[rs[d] + pos] = src[i];
}

// ------ softmax stats + per-edge alpha, one wave per (node, head) -----------
__global__ __launch_bounds__(256) void gat_stats(const float* __restrict__ asrc,
        const float* __restrict__ adst, const int* __restrict__ rs,
        const int* __restrict__ csr, float* __restrict__ alph,
        float* __restrict__ aself, int n)
{
    int g = blockIdx.x * 4 + (threadIdx.x >> 6);
    int lane = threadIdx.x & 63;
    int node = g >> 2, head = g & 3;
    if (node >= n) return;
    int e0 = rs[node], e1 = rs[node + 1];
    float adn  = adst[node * 4 + head];
    float slog = leaky(asrc[node * 4 + head] + adn);
    float mx = slog;
    for (int j = e0 + lane; j < e1; j += 64){
        int s = csr[j];
        mx = fmaxf(mx, leaky(asrc[s * 4 + head] + adn));
    }
#pragma unroll
    for (int off = 32; off > 0; off >>= 1) mx = fmaxf(mx, __shfl_xor(mx, off));
    float lsum = 0.f;
    for (int j = e0 + lane; j < e1; j += 64){
        int s = csr[j];
        lsum += expf(leaky(asrc[s * 4 + head] + adn) - mx);
    }
#pragma unroll
    for (int off = 32; off > 0; off >>= 1) lsum += __shfl_xor(lsum, off);
    float es  = expf(slog - mx);
    float inv = 1.f / (lsum + es);
    for (int j = e0 + lane; j < e1; j += 64){
        int s = csr[j];
        alph[(size_t)j * 4 + head] = expf(leaky(asrc[s * 4 + head] + adn) - mx) * inv;
    }
    if (lane == 0) aself[node * 4 + head] = es * inv;
}

// ---- aggregation: one wave per node, 8 features/lane (all 4 heads) ---------
__global__ __launch_bounds__(256) void gat_gather(const float* __restrict__ h,
        const float* __restrict__ alph, const float* __restrict__ aself,
        const int* __restrict__ rs, const int* __restrict__ csr,
        const float* __restrict__ bias, float* __restrict__ out, int n)
{
    int node = blockIdx.x * 4 + (threadIdx.x >> 6);
    int lane = threadIdx.x & 63;
    if (node >= n) return;
    int e0 = rs[node], e1 = rs[node + 1];
    int f0 = lane * 8;
    int head = lane >> 4;
    float4 acc0, acc1;
    {   // self loop
        float a = aself[node * 4 + head];
        const float4* hp = reinterpret_cast<const float4*>(&h[(size_t)node * FDIM + f0]);
        float4 v0 = hp[0], v1 = hp[1];
        acc0 = make_float4(a * v0.x, a * v0.y, a * v0.z, a * v0.w);
        acc1 = make_float4(a * v1.x, a * v1.y, a * v1.z, a * v1.w);
    }
    int j = e0;
    for (; j + 2 <= e1; j += 2){
        int s0 = csr[j], s1 = csr[j + 1];
        float a0 = alph[(size_t)j * 4 + head];
        float a1 = alph[(size_t)(j + 1) * 4 + head];
        const float4* p0 = reinterpret_cast<const float4*>(&h[(size_t)s0 * FDIM + f0]);
        const float4* p1 = reinterpret_cast<const float4*>(&h[(size_t)s1 * FDIM + f0]);
        float4 u0 = p0[0], u1 = p0[1];
        float4 w0 = p1[0], w1 = p1[1];
        acc0.x += a0 * u0.x + a1 * w0.x;  acc0.y += a0 * u0.y + a1 * w0.y;
        acc0.z += a0 * u0.z + a1 * w0.z;  acc0.w += a0 * u0.w + a1 * w0.w;
        acc1.x += a0 * u1.x + a1 * w1.x;  acc1.y += a0 * u1.y + a1 * w1.y;
        acc1.z += a0 * u1.z + a1 * w1.z;  acc1.w += a0 * u1.w + a1 * w1.w;
    }
    if (j < e1){
        int s0 = csr[j];
        float a0 = alph[(size_t)j * 4 + head];
        const float4* p0 = reinterpret_cast<const float4*>(&h[(size_t)s0 * FDIM + f0]);
        float4 u0 = p0[0], u1 = p0[1];
        acc0.x += a0 * u0.x;  acc0.y += a0 * u0.y;
        acc0.z += a0 * u0.z;  acc0.w += a0 * u0.w;
        acc1.x += a0 * u1.x;  acc1.y += a0 * u1.y;
        acc1.z += a0 * u1.z;  acc1.w += a0 * u1.w;
    }
    const float4* bp = reinterpret_cast<const float4*>(&bias[f0]);
    float4 b0 = bp[0], b1 = bp[1];
    float4 o0 = make_float4(elu(acc0.x + b0.x), elu(acc0.y + b0.y),
                            elu(acc0.z + b0.z), elu(acc0.w + b0.w));
    float4 o1 = make_float4(elu(acc1.x + b1.x), elu(acc1.y + b1.y),
                            elu(acc1.z + b1.z), elu(acc1.w + b1.w));
    float4* op = reinterpret_cast<float4*>(&out[(size_t)node * FDIM + f0]);
    op[0] = o0; op[1] = o1;
}

// ------------------------- pooling ------------------------------------------
__global__ __launch_bounds__(512) void pw_norm(const float* __restrict__ w, float* __restrict__ invn){
    __shared__ float red[8];
    int t = threadIdx.x;
    float s = w[t] * w[t];
#pragma unroll
    for (int off = 32; off > 0; off >>= 1) s += __shfl_xor(s, off);
    if ((t & 63) == 0) red[t >> 6] = s;
    __syncthreads();
    if (t == 0){
        float a = 0;
        for (int i = 0; i < 8; ++i) a += red[i];
        *invn = rsqrtf(a);
    }
}

__global__ __launch_bounds__(256) void pool_score(const float* __restrict__ x, const float* __restrict__ w,
        const float* __restrict__ invn, float* __restrict__ score, int n){
    int g = blockIdx.x * 4 + (threadIdx.x >> 6);
    int lane = threadIdx.x & 63;
    if (g >= n) return;
    const float* xp = x + (size_t)g * FDIM;
    float s = 0.f;
#pragma unroll
    for (int q = 0; q < 8; ++q) s += xp[q * 64 + lane] * w[q * 64 + lane];
#pragma unroll
    for (int off = 32; off > 0; off >>= 1) s += __shfl_xor(s, off);
    if (lane == 0) score[g] = tanhf(s * (*invn));
}

// exact k-th threshold by 4x 8-bit radix passes; sel[0]=thresh key, sel[1]=#ties to keep
__global__ __launch_bounds__(1024) void radix_select(const float* __restrict__ score, int n, int k,
                                                     unsigned* __restrict__ sel){
    __shared__ unsigned hist[256];
    __shared__ unsigned s_prefix, s_rem;
    int t = threadIdx.x;
    if (t == 0){ s_prefix = 0u; s_rem = (unsigned)k; }
    if (t < 256) hist[t] = 0u;
    __syncthreads();
    for (int pass = 3; pass >= 0; --pass){
        unsigned shift = (unsigned)pass * 8u;
        unsigned pmask = (pass == 3) ? 0u : (0xFFFFFFFFu << (shift + 8u));
        unsigned pref = s_prefix;
        for (int i = t; i < n; i += 1024){
            unsigned key = ordkey(score[i]);
            if ((key & pmask) == pref) atomicAdd(&hist[(key >> shift) & 255u], 1u);
        }
        __syncthreads();
        if (t == 0){
            unsigned rem = s_rem, acc = 0, d = 255;
            for (;;){
                unsigned c = hist[d];
                if (acc + c >= rem) break;
                acc += c;
                if (d == 0) break;
                --d;
            }
            s_prefix = pref | (d << shift);
            s_rem = rem - acc;
        }
        __syncthreads();
        if (t < 256) hist[t] = 0u;
        __syncthreads();
    }
    if (t == 0){ sel[0] = s_prefix; sel[1] = s_rem; }
}

// sel[2]=tie ticket, sel[3]=kept counter (both pre-zeroed)
__global__ void pool_compact(const float* __restrict__ score, int n,
                             unsigned* __restrict__ sel, int* __restrict__ remap,
                             int* __restrict__ oldidx){
    int i = blockIdx.x * 256 + threadIdx.x;
    if (i >= n) return;
    unsigned T = sel[0], ties = sel[1];
    unsigned key = ordkey(score[i]);
    int keep = 0;
    if (key > T) keep = 1;
    else if (key == T){
        unsigned tk = atomicAdd(&sel[2], 1u);
        if (tk < ties) keep = 1;
    }
    if (keep){
        int pos = (int)atomicAdd(&sel[3], 1u);
        remap[i] = pos;
        oldidx[pos] = i;
    } else remap[i] = -1;
}

__global__ __launch_bounds__(256) void pool_gather(const float* __restrict__ x, const int* __restrict__ oldidx,
        const float* __restrict__ score, float* __restrict__ xn, int k){
    int j = blockIdx.x;
    if (j >= k) return;
    int old = oldidx[j];
    float v = score[old];
    for (int f = threadIdx.x; f < FDIM; f += 256)
        xn[(size_t)j * FDIM + f] = x[(size_t)old * FDIM + f] * v;
}

__global__ void edge_remap(const int* __restrict__ src, const int* __restrict__ dst,
                           const int* __restrict__ remap, int* __restrict__ src2,
                           int* __restrict__ dst2, int e){
    int i = blockIdx.x * 256 + threadIdx.x;
    if (i >= e) return;
    int s = remap[src[i]], d = remap[dst[i]];
    if (s >= 0 && d >= 0){ src2[i] = s; dst2[i] = d; }
    else { src2[i] = -1; dst2[i] = -1; }
}

// ----------------- readout --------------------------------------------------
__global__ __launch_bounds__(512) void final_reduce(const float* __restrict__ x, const int* __restrict__ oldidx,
        const float* __restrict__ score, int k, float* __restrict__ gsum){
    int t = threadIdx.x; // 512
    float a = 0.f;
    for (int j = blockIdx.x; j < k; j += gridDim.x){
        int o = oldidx[j];
        a += x[(size_t)o * FDIM + t] * score[o];
    }
    atomicAdd(&gsum[t], a);
}

__global__ __launch_bounds__(640) void final_gemm(const float* __restrict__ g, const float* __restrict__ Wl,
        const float* __restrict__ bl, float* __restrict__ out){
    int w = threadIdx.x >> 6;   // 0..9
    int lane = threadIdx.x & 63;
    float s = 0.f;
    for (int f = lane; f < FDIM; f += 64) s += g[f] * Wl[f * 10 + w];
#pragma unroll
    for (int off = 32; off > 0; off >>= 1) s += __shfl_xor(s, off);
    if (lane == 0) out[w] = s * (1.0f / K2_KEEP) + bl[w];
}

extern "C" void kernel_launch(void* const* d_in, const int* in_sizes, int n_in,
                              void* d_out, int out_size, void* d_ws, size_t ws_size,
                              hipStream_t stream)
{
    (void)in_sizes; (void)n_in; (void)out_size; (void)ws_size;
    const float* x   = (const float*)d_in[0];
    const int*   ei  = (const int*)  d_in[1];
    const float* W1  = (const float*)d_in[3];
    const float* as1 = (const float*)d_in[4];
    const float* ad1 = (const float*)d_in[5];
    const float* b1  = (const float*)d_in[6];
    const float* pw1 = (const float*)d_in[7];
    const float* W2  = (const float*)d_in[8];
    const float* as2 = (const float*)d_in[9];
    const float* ad2 = (const float*)d_in[10];
    const float* b2  = (const float*)d_in[11];
    const float* pw2 = (const float*)d_in[12];
    const float* Wl  = (const float*)d_in[13];
    const float* bl  = (const float*)d_in[14];
    const int* src1 = ei;
    const int* dst1 = ei + E_EDGES;

    char* wsb = (char*)d_ws;
    size_t off = 0;
    auto alloc = [&](size_t bytes) -> char* {
        char* p = wsb + off;
        off += (bytes + 255) & ~(size_t)255;
        return p;
    };
    float* h1   = (float*)alloc((size_t)N_NODES * FDIM * 4);  // reused: h2 + out2
    float* out1 = (float*)alloc((size_t)N_NODES * FDIM * 4);
    float* x2   = (float*)alloc((size_t)K1_KEEP * FDIM * 4);
    float* asrc = (float*)alloc((size_t)N_NODES * NHEAD * 4);
    float* adst = (float*)alloc((size_t)N_NODES * NHEAD * 4);
    float* alph = (float*)alloc((size_t)E_EDGES * NHEAD * 4);
    float* aself= (float*)alloc((size_t)N_NODES * NHEAD * 4);
    float* score= (float*)alloc((size_t)N_NODES * 4);
    float* invn = (float*)alloc(4);
    unsigned* sel = (unsigned*)alloc(16);
    int* cnt  = (int*)alloc((size_t)(N_NODES + 1) * 4);
    int* rsx  = (int*)alloc((size_t)(N_NODES + 1) * 4);
    int* tmp  = (int*)alloc((size_t)N_NODES * 4);
    int* csr  = (int*)alloc((size_t)E_EDGES * 4);
    int* src2 = (int*)alloc((size_t)E_EDGES * 4);
    int* dst2 = (int*)alloc((size_t)E_EDGES * 4);
    int* remap= (int*)alloc((size_t)N_NODES * 4);
    int* oldi = (int*)alloc((size_t)K1_KEEP * 4);
    float* gsum = (float*)alloc(512 * 4);
    float* h2   = h1;                            // layer-2 aliases into h1 region
    float* out2 = h1 + (size_t)K1_KEEP * FDIM;   // N*F == 2*K1*F, fits exactly

    // ---- layer 1 (GAT on N nodes, E edges + self loops) ----
    int gx1 = (N_NODES + 63) / 64;
    gemm_tile<64><<<gx1 * 4, 256, 0, stream>>>(x, W1, h1, N_NODES);
    attn_scores<<<N_NODES, 256, 0, stream>>>(h1, as1, ad1, asrc, adst, N_NODES);
    hipMemsetAsync(cnt, 0, (size_t)N_NODES * 4, stream);
    edge_count<<<(E_EDGES + 255) / 256, 256, 0, stream>>>(dst1, E_EDGES, cnt);
    exscan<<<1, 1024, 0, stream>>>(cnt, N_NODES, rsx);
    hipMemsetAsync(tmp, 0, (size_t)N_NODES * 4, stream);
    edge_fill<<<(E_EDGES + 255) / 256, 256, 0, stream>>>(src1, dst1, E_EDGES, rsx, tmp, csr);
    gat_stats<<<N_NODES, 256, 0, stream>>>(asrc, adst, rsx, csr, alph, aself, N_NODES);
    gat_gather<<<(N_NODES + 3) / 4, 256, 0, stream>>>(h1, alph, aself, rsx, csr, b1, out1, N_NODES);

    // ---- pool 1 (keep K1) ----
    pw_norm<<<1, 512, 0, stream>>>(pw1, invn);
    pool_score<<<(N_NODES + 3) / 4, 256, 0, stream>>>(out1, pw1, invn, score, N_NODES);
    hipMemsetAsync(sel, 0, 16, stream);
    radix_select<<<1, 1024, 0, stream>>>(score, N_NODES, K1_KEEP, sel);
    pool_compact<<<(N_NODES + 255) / 256, 256, 0, stream>>>(score, N_NODES, sel, remap, oldi);
    pool_gather<<<K1_KEEP, 256, 0, stream>>>(out1, oldi, score, x2, K1_KEEP);
    edge_remap<<<(E_EDGES + 255) / 256, 256, 0, stream>>>(src1, dst1, remap, src2, dst2, E_EDGES);

    // ---- layer 2 (GAT on K1 nodes, masked edges + self loops) ----
    int gx2 = (K1_KEEP + 63) / 64;
    gemm_tile<512><<<gx2 * 4, 256, 0, stream>>>(x2, W2, h2, K1_KEEP);
    attn_scores<<<K1_KEEP, 256, 0, stream>>>(h2, as2, ad2, asrc, adst, K1_KEEP);
    hipMemsetAsync(cnt, 0, (size_t)K1_KEEP * 4, stream);
    edge_count<<<(E_EDGES + 255) / 256, 256, 0, stream>>>(dst2, E_EDGES, cnt);
    exscan<<<1, 1024, 0, stream>>>(cnt, K1_KEEP, rsx);
    hipMemsetAsync(tmp, 0, (size_t)K1_KEEP * 4, stream);
    edge_fill<<<(E_EDGES + 255) / 256, 256, 0, stream>>>(src2, dst2, E_EDGES, rsx, tmp, csr);
    gat_stats<<<K1_KEEP, 256, 0, stream>>>(asrc, adst, rsx, csr, alph, aself, K1_KEEP);
    gat_gather<<<(K1_KEEP + 3) / 4, 256, 0, stream>>>(h2, alph, aself, rsx, csr, b2, out2, K1_KEEP);

    // ---- pool 2 (keep K2) + readout ----
    pw_norm<<<1, 512, 0, stream>>>(pw2, invn);
    pool_score<<<(K1_KEEP + 3) / 4, 256, 0, stream>>>(out2, pw2, invn, score, K1_KEEP);
    hipMemsetAsync(sel, 0, 16, stream);
    radix_select<<<1, 1024, 0, stream>>>(score, K1_KEEP, K2_KEEP, sel);
    pool_compact<<<(K1_KEEP + 255) / 256, 256, 0, stream>>>(score, K1_KEEP, sel, remap, oldi);
    hipMemsetAsync(gsum, 0, 512 * 4, stream);
    final_reduce<<<64, 512, 0, stream>>>(out2, oldi, score, K2_KEEP, gsum);
    final_gemm<<<1, 640, 0, stream>>>(gsum, Wl, bl, (float*)d_out);
}